// Round 5
// baseline (731.258 us; speedup 1.0000x reference)
//
#include <hip/hip_runtime.h>
#include <stdint.h>

static constexpr int BATCH = 16;
static constexpr int Hh = 1024;
static constexpr int Ww = 1024;
static constexpr int HW = Hh * Ww;        // 2^20
static constexpr int NPIX = BATCH * HW;   // 2^24
static constexpr int TS = 64;             // tile side (64x64 local CCL)
static constexpr int TPIX = TS * TS;      // 4096 pixels per tile
static constexpr int TILES_PER_IMG = (Hh / TS) * (Ww / TS);   // 256

// argmax stage-1 geometry: each block reduces CHUNK counts
static constexpr int CHUNK = 1024;
static constexpr int NBLK1 = NPIX / CHUNK;          // 16384 (1024 per batch)
static constexpr int BLK1_PER_B = HW / CHUNK;       // 1024

// ---------------- global union-find (Komura/Playne atomic min-link) --------

// Path-halving find: ONLY safe during the merge phase (k_border), where the
// merge retry loop re-establishes any link displaced by a racing plain store.
__device__ __forceinline__ int find_root_halve(int* parent, int i) {
    while (true) {
        int p = parent[i];
        if (p == i) return i;
        int gp = parent[p];
        if (gp == p) return p;
        parent[i] = gp;        // plain store of an ancestor — merge-phase safe
        i = gp;
    }
}

// Read-only find: used in k_roots. Safe concurrently with k_roots' own
// parent[r]=final stores because those stores only ever write FINAL roots
// (self-terminating), never mid-chain ancestors.
__device__ __forceinline__ int find_root_ro(const int* parent, int i) {
    int p = parent[i];
    while (p != i) { i = p; p = parent[i]; }
    return i;
}

__device__ __forceinline__ void merge_uf(int* parent, int a, int b) {
    while (true) {
        a = find_root_halve(parent, a);
        b = find_root_halve(parent, b);
        if (a == b) return;
        if (a > b) { int t = a; a = b; b = t; }   // ensure a < b
        int old = atomicMin(&parent[b], a);
        if (old == b) return;   // b was a root and we linked it under a
        b = old;                // someone else linked b first; merge with that
    }
}

// ---------------- K1: per-tile run-based CCL (wave = row) ------------------
// 64x64 tile, 256 threads = 4 waves; each wave owns full 64-px rows, so one
// __ballot gives the row's fg mask. Horizontal connectivity = free bit math
// (runs). UF nodes = run starts only (~16/row). Vertical merges deduplicated
// to ~one per connected run pair via mask rules:
//   R1: up[l] fg and (l==runstart or !up[l-1])  -> merge(myrun, uprun(l))
//   R2: l==runstart and !up[l] and up[l-1]      -> merge(myrun, uprun(l-1))
//   R3: l==runend   and !up[l] and up[l+1]      -> merge(myrun, uprun(l+1))
// counts[i] > 0 afterwards IFF i is an original tile root (free root flag).

__global__ __launch_bounds__(256) void k_local(const float* __restrict__ x,
                                               int* __restrict__ parent,
                                               int* __restrict__ counts,
                                               unsigned long long* __restrict__ best) {
    __shared__ int lab[TPIX];
    __shared__ int cnt[TPIX];
    __shared__ unsigned long long rowmask[TS];

    int tile = blockIdx.x;          // 16 images * 256 tiles
    int b = tile >> 8;
    int t = tile & 255;
    int th = t >> 4, tw = t & 15;
    int h0 = th * TS, w0 = tw * TS;
    const float* xb = x + (size_t)b * 2 * (size_t)HW;
    int base = b * HW + h0 * Ww + w0;   // global idx of local (0,0)
    int wv = threadIdx.x >> 6;
    int lane = threadIdx.x & 63;

    if (tile == 0 && threadIdx.x < BATCH) best[threadIdx.x] = 0ull;

    // Phase A: load fg, build row masks, init run-start labels, zero cnt/counts
    #pragma unroll
    for (int k = 0; k < TS / 4; k++) {
        int r = (k << 2) | wv;
        int off = (h0 + r) * Ww + w0 + lane;
        float x0 = xb[off];
        float x1 = xb[off + HW];
        bool fg = x1 > x0;
        unsigned long long m = __ballot(fg);
        if (lane == 0) rowmask[r] = m;
        counts[base + r * Ww + lane] = 0;
        int p = (r << 6) | lane;
        cnt[p] = 0;
        unsigned long long zb = ~m & ((1ull << lane) - 1);   // clear bits below
        int b0 = zb ? (64 - __clzll(zb)) : 0;                // my run start
        lab[p] = (fg && lane == b0) ? p : -1;
    }
    __syncthreads();

    // LDS union-find on run-start nodes (path halving; retry loop makes
    // racing ancestor stores safe, same argument as find_root_halve).
    auto find_lh = [&](int i) {
        while (true) {
            int p = lab[i];
            if (p == i) return i;
            int gp = lab[p];
            if (gp == p) return p;
            lab[i] = gp;
            i = gp;
        }
    };
    auto merge_l = [&](int a, int c) {
        while (true) {
            a = find_lh(a); c = find_lh(c);
            if (a == c) return;
            if (a > c) { int tt = a; a = c; c = tt; }
            int old = atomicMin(&lab[c], a);
            if (old == c) return;
            c = old;
        }
    };

    // Phase B: deduplicated vertical run merges
    #pragma unroll
    for (int k = 0; k < TS / 4; k++) {
        int r = (k << 2) | wv;
        if (r == 0) continue;
        unsigned long long m = rowmask[r];
        bool fg = (m >> lane) & 1;
        if (!fg) continue;
        unsigned long long mu = rowmask[r - 1];
        unsigned long long zb = ~m & ((1ull << lane) - 1);
        int b0 = zb ? (64 - __clzll(zb)) : 0;
        int p0 = (r << 6) | b0;                       // my run-start node
        bool upC = (mu >> lane) & 1;
        bool upL = (lane > 0)  && ((mu >> (lane - 1)) & 1);
        bool upR = (lane < 63) && ((mu >> (lane + 1)) & 1);
        bool atStart = (lane == b0);
        bool atEnd = (lane == 63) || !((m >> (lane + 1)) & 1);
        auto ustart = [&](int lu) {
            unsigned long long zbu = ~mu & ((1ull << lu) - 1);
            int u0 = zbu ? (64 - __clzll(zbu)) : 0;
            return ((r - 1) << 6) | u0;
        };
        if (upC && (atStart || !upL)) merge_l(p0, ustart(lane));
        if (atStart && !upC && upL)   merge_l(p0, ustart(lane - 1));
        if (atEnd && !upC && upR)     merge_l(p0, ustart(lane + 1));
    }
    __syncthreads();

    // Phase C: run starts fold run length into root + full-compress own node
    #pragma unroll
    for (int k = 0; k < TS / 4; k++) {
        int r = (k << 2) | wv;
        unsigned long long m = rowmask[r];
        bool fg = (m >> lane) & 1;
        bool atStart = fg && ((lane == 0) || !((m >> (lane - 1)) & 1));
        if (!atStart) continue;
        int p = (r << 6) | lane;
        unsigned long long za = (~m) >> lane;         // bit0 corresponds to lane (==0)
        int len = za ? (__ffsll(za) - 1) : (64 - lane);
        // read-only find (stores below only ever write final roots — safe)
        int root = p;
        { int q = lab[root]; while (q != root) { root = q; q = lab[root]; } }
        if (root != p) lab[p] = root;                 // sole write to lab[p]
        atomicAdd(&cnt[root], len);
    }
    __syncthreads();

    // Phase D: per-pixel label write (1 LDS broadcast read) + count publish
    #pragma unroll
    for (int k = 0; k < TS / 4; k++) {
        int r = (k << 2) | wv;
        unsigned long long m = rowmask[r];
        bool fg = (m >> lane) & 1;
        int g = base + r * Ww + lane;
        unsigned long long zb = ~m & ((1ull << lane) - 1);
        int b0 = zb ? (64 - __clzll(zb)) : 0;
        int p0 = (r << 6) | b0;
        int rt = lab[p0];                             // broadcast within run
        parent[g] = fg ? (base + (rt >> 6) * Ww + (rt & 63)) : -1;
        if (fg && lane == b0 && rt == p0) counts[g] = cnt[p0];  // roots only
    }
}

// ---------------- K2: cross-tile border merges (border threads only) -------
// Per batch: group A = rows h%64==0 (16*1024 px), group B = cols w%64 in
// {0,63} (1024*32 px). Corner pixels appear in both groups; merge_uf is
// idempotent so duplicate processing is harmless.

static constexpr int BORDER_A = (Hh / TS) * Ww;                 // 16384
static constexpr int BORDER_PER_B = BORDER_A + Hh * (Ww / TS) * 2;  // 49152

__global__ __launch_bounds__(256) void k_border(int* __restrict__ parent) {
    int b = blockIdx.y;
    int t = blockIdx.x * blockDim.x + threadIdx.x;
    int h, w;
    if (t < BORDER_A) {
        h = (t >> 10) << 6;             // 0,64,...,960
        w = t & 1023;
    } else {
        int t2 = t - BORDER_A;          // 0..32767
        int c = t2 & 31;                // 32 border columns (16 tiles x 2 edges)
        h = t2 >> 5;                    // 0..1023
        w = ((c >> 1) << 6) + ((c & 1) ? (TS - 1) : 0);
    }
    int i = b * HW + h * Ww + w;
    if (parent[i] < 0) return;
    bool hb = (h & (TS - 1)) == 0;
    bool wb = (w & (TS - 1)) == 0;
    bool we = (w & (TS - 1)) == (TS - 1);
    if (wb && w > 0 && parent[i - 1] >= 0) merge_uf(parent, i, i - 1);
    if (h > 0) {
        if (hb && parent[i - Ww] >= 0) merge_uf(parent, i, i - Ww);
        if ((hb | wb) && w > 0 && parent[i - Ww - 1] >= 0) merge_uf(parent, i, i - Ww - 1);
        if ((hb | we) && w < Ww - 1 && parent[i - Ww + 1] >= 0) merge_uf(parent, i, i - Ww + 1);
    }
}

// ---------------- K3: root-only compress + hierarchical count fold ---------
// counts[i] > 0 <=> i is an original tile root. Chains pass only through
// tile roots, so compressing these makes every pixel's root reachable in
// 2 hops. Count folding does one atomic per NON-final tile root; fold
// targets are scattered so they parallelize across batches/components.

__global__ __launch_bounds__(256) void k_roots(int* __restrict__ parent,
                                               int* __restrict__ counts) {
    int i = blockIdx.x * blockDim.x + threadIdx.x;
    int c = counts[i];
    if (c <= 0) return;                      // not an original tile root
    int root = find_root_ro(parent, i);
    if (root != i) {
        parent[i] = root;                    // full compression of root nodes
        atomicAdd(&counts[root], c);         // fold my count into final root
        counts[i] = 0;                       // only final roots keep counts
    }
}

// ---------------- K4a: per-block argmax (NO atomics) -----------------------
// Each block reduces CHUNK=1024 consecutive counts (4/thread, coalesced) to
// one packed (count<<32 | ~index) candidate, plain-stored to blockmax.
// Blocks never straddle a batch (HW % CHUNK == 0).

__global__ __launch_bounds__(256) void k_argmax1(const int* __restrict__ counts,
                                                 unsigned long long* __restrict__ blockmax) {
    int base = blockIdx.x * CHUNK;
    unsigned long long v = 0ull;
    #pragma unroll
    for (int k = 0; k < 4; k++) {
        int i = base + threadIdx.x + k * 256;
        int c = counts[i];
        if (c > 0) {
            unsigned long long o =
                (((unsigned long long)(unsigned)c) << 32) |
                (unsigned long long)(0xFFFFFFFFu - (unsigned)i);
            if (o > v) v = o;
        }
    }
    for (int off = 32; off > 0; off >>= 1) {
        unsigned long long o = __shfl_down(v, off);
        if (o > v) v = o;
    }
    __shared__ unsigned long long sm[4];
    if ((threadIdx.x & 63) == 0) sm[threadIdx.x >> 6] = v;
    __syncthreads();
    if (threadIdx.x == 0) {
        v = sm[0];
        #pragma unroll
        for (int w = 1; w < 4; w++) if (sm[w] > v) v = sm[w];
        blockmax[blockIdx.x] = v;            // plain coalesced store
    }
}

// ---------------- K4b: per-batch final argmax (NO atomics) -----------------

__global__ __launch_bounds__(256) void k_argmax2(const unsigned long long* __restrict__ blockmax,
                                                 unsigned long long* __restrict__ best) {
    int b = blockIdx.x;
    const unsigned long long* src = blockmax + b * BLK1_PER_B;
    unsigned long long v = 0ull;
    #pragma unroll
    for (int k = 0; k < BLK1_PER_B / 256; k++) {
        unsigned long long o = src[threadIdx.x + k * 256];
        if (o > v) v = o;
    }
    for (int off = 32; off > 0; off >>= 1) {
        unsigned long long o = __shfl_down(v, off);
        if (o > v) v = o;
    }
    __shared__ unsigned long long sm[4];
    if ((threadIdx.x & 63) == 0) sm[threadIdx.x >> 6] = v;
    __syncthreads();
    if (threadIdx.x == 0) {
        v = sm[0];
        #pragma unroll
        for (int w = 1; w < 4; w++) if (sm[w] > v) v = sm[w];
        best[b] = v;                         // plain store, one per batch
    }
}

// ---------------- K5: apply mask (2-hop root lookup) -----------------------
// parent[i] is some original tile root (possibly i itself); after k_roots
// every tile root points directly at its final root, so root(i) =
// parent[parent[i]] exactly.

__global__ __launch_bounds__(256) void k_final(const float* __restrict__ x,
                                               const int* __restrict__ parent,
                                               const unsigned long long* __restrict__ best,
                                               float* __restrict__ out) {
    int i = blockIdx.x * blockDim.x + threadIdx.x;
    int b = i >> 20;
    int p = i & (HW - 1);
    unsigned long long bv = best[b];
    int broot = (int)(0xFFFFFFFFu - (unsigned)(bv & 0xFFFFFFFFull));
    int pr = parent[i];
    int a = (pr >= 0) ? pr : 0;              // safe dummy index for bg
    int root = parent[a];                    // mostly-broadcast gather
    bool mask = (pr >= 0) && (root == broot);
    const float* xb = x + ((size_t)b * 2) * (size_t)HW;
    float* ob = out + ((size_t)b * 2) * (size_t)HW;
    float x0 = xb[p];
    float x1 = xb[p + HW];
    ob[p]      = mask ? x0 : 0.0f;
    ob[p + HW] = mask ? x1 : 0.0f;
}

// ---------------- launch ---------------------------------------------------

extern "C" void kernel_launch(void* const* d_in, const int* in_sizes, int n_in,
                              void* d_out, int out_size, void* d_ws, size_t ws_size,
                              hipStream_t stream) {
    const float* x = (const float*)d_in[0];
    float* out = (float*)d_out;

    // workspace layout:
    //   best[16] u64 (256B pad) | parent[NPIX] i32 | counts[NPIX] i32 |
    //   blockmax[NBLK1] u64 (128KB)
    unsigned long long* best = (unsigned long long*)d_ws;
    int* parent = (int*)((char*)d_ws + 256);
    int* counts = parent + NPIX;
    unsigned long long* blockmax = (unsigned long long*)(counts + NPIX);

    dim3 blk(256);
    dim3 grd(NPIX / 256);
    dim3 grd_tiles(BATCH * TILES_PER_IMG);           // 4096 tiles
    dim3 grd_border(BORDER_PER_B / 256, BATCH);      // 192 x 16 blocks

    k_local   <<<grd_tiles, blk, 0, stream>>>(x, parent, counts, best);
    k_border  <<<grd_border, blk, 0, stream>>>(parent);
    k_roots   <<<grd, blk, 0, stream>>>(parent, counts);
    k_argmax1 <<<dim3(NBLK1), blk, 0, stream>>>(counts, blockmax);
    k_argmax2 <<<dim3(BATCH), blk, 0, stream>>>(blockmax, best);
    k_final   <<<grd, blk, 0, stream>>>(x, parent, best, out);
}

// Round 6
// 602.323 us; speedup vs baseline: 1.2141x; 1.2141x over previous
//
#include <hip/hip_runtime.h>
#include <stdint.h>

static constexpr int BATCH = 16;
static constexpr int Hh = 1024;
static constexpr int Ww = 1024;
static constexpr int HW = Hh * Ww;        // 2^20
static constexpr int NPIX = BATCH * HW;   // 2^24
static constexpr int TS = 64;             // tile side (64x64 local CCL)
static constexpr int TILES_PER_IMG = (Hh / TS) * (Ww / TS);   // 256
static constexpr int NODES = TS * 32;     // run nodes: <=32 runs per 64px row

// argmax stage-1 geometry: each block reduces CHUNK counts
static constexpr int CHUNK = 1024;
static constexpr int NBLK1 = NPIX / CHUNK;          // 16384 (1024 per batch)
static constexpr int BLK1_PER_B = HW / CHUNK;       // 1024

// ---------------- global union-find (Komura/Playne atomic min-link) --------

// Path-halving find: ONLY safe during the merge phase (k_border), where the
// merge retry loop re-establishes any link displaced by a racing plain store.
__device__ __forceinline__ int find_root_halve(int* parent, int i) {
    while (true) {
        int p = parent[i];
        if (p == i) return i;
        int gp = parent[p];
        if (gp == p) return p;
        parent[i] = gp;        // plain store of an ancestor — merge-phase safe
        i = gp;
    }
}

// Read-only find: used in k_roots. Safe concurrently with k_roots' own
// parent[r]=final stores because those stores only ever write FINAL roots
// (self-terminating), never mid-chain ancestors.
__device__ __forceinline__ int find_root_ro(const int* parent, int i) {
    int p = parent[i];
    while (p != i) { i = p; p = parent[i]; }
    return i;
}

__device__ __forceinline__ void merge_uf(int* parent, int a, int b) {
    while (true) {
        a = find_root_halve(parent, a);
        b = find_root_halve(parent, b);
        if (a == b) return;
        if (a > b) { int t = a; a = b; b = t; }   // ensure a < b
        int old = atomicMin(&parent[b], a);
        if (old == b) return;   // b was a root and we linked it under a
        b = old;                // someone else linked b first; merge with that
    }
}

// ---------------- K1: per-tile run-based CCL, compact run nodes ------------
// 64x64 tile, 256 threads = 4 waves; each wave owns full 64-px rows, so one
// __ballot gives the row's fg mask. Horizontal connectivity = free bit math.
// UF node = (row<<5)|run_index (<=32 runs/row) -> lab/cnt arrays of 2048.
// Vertical merges deduplicated to ~one per connected run pair via:
//   R1: up[l] fg and (l==runstart or !up[l-1])  -> merge(myrun, uprun(l))
//   R2: l==runstart and !up[l] and up[l-1]      -> merge(myrun, uprun(l-1))
//   R3: l==runend   and !up[l] and up[l+1]      -> merge(myrun, uprun(l+1))
// Count fold is wave-aggregated (one LDS atomic per wave x distinct root).
// counts[i] > 0 afterwards IFF i is an original tile root (free root flag).

__global__ __launch_bounds__(256) void k_local(const float* __restrict__ x,
                                               int* __restrict__ parent,
                                               int* __restrict__ counts,
                                               unsigned long long* __restrict__ best) {
    __shared__ int lab[NODES];
    __shared__ int cnt[NODES];
    __shared__ unsigned char runpos[NODES];
    __shared__ unsigned long long rowmask[TS];

    int tile = blockIdx.x;          // 16 images * 256 tiles
    int b = tile >> 8;
    int t = tile & 255;
    int th = t >> 4, tw = t & 15;
    int h0 = th * TS, w0 = tw * TS;
    const float* xb = x + (size_t)b * 2 * (size_t)HW;
    int base = b * HW + h0 * Ww + w0;   // global idx of local (0,0)
    int wv = threadIdx.x >> 6;
    int lane = threadIdx.x & 63;
    unsigned long long below = (lane == 0) ? 0ull : ((1ull << lane) - 1);

    if (tile == 0 && threadIdx.x < BATCH) best[threadIdx.x] = 0ull;

    // node table init (self-roots, zero counts)
    #pragma unroll
    for (int k = 0; k < NODES / 256; k++) {
        int i = threadIdx.x + k * 256;
        lab[i] = i;
        cnt[i] = 0;
    }

    // Phase A: load fg, build row masks, register run starts
    #pragma unroll
    for (int k = 0; k < TS / 4; k++) {
        int r = (k << 2) | wv;
        int off = (h0 + r) * Ww + w0 + lane;
        float x0 = xb[off];
        float x1 = xb[off + HW];
        bool fg = x1 > x0;
        unsigned long long m = __ballot(fg);
        if (lane == 0) rowmask[r] = m;
        unsigned long long rs = m & ~(m << 1);       // run-start mask
        if ((rs >> lane) & 1) {
            int node = (r << 5) | (int)__popcll(rs & below);
            runpos[node] = (unsigned char)lane;
        }
    }
    __syncthreads();

    // LDS union-find on run nodes (path halving; retry loop makes racing
    // ancestor stores safe, same argument as find_root_halve).
    auto find_lh = [&](int i) {
        while (true) {
            int p = lab[i];
            if (p == i) return i;
            int gp = lab[p];
            if (gp == p) return p;
            lab[i] = gp;
            i = gp;
        }
    };
    auto merge_l = [&](int a, int c) {
        while (true) {
            a = find_lh(a); c = find_lh(c);
            if (a == c) return;
            if (a > c) { int tt = a; a = c; c = tt; }
            int old = atomicMin(&lab[c], a);
            if (old == c) return;
            c = old;
        }
    };

    // Phase B: deduplicated vertical run merges
    for (int k = 0; k < TS / 4; k++) {
        int r = (k << 2) | wv;
        if (r == 0) continue;
        unsigned long long m = rowmask[r];
        bool fg = (m >> lane) & 1;
        if (!fg) continue;
        unsigned long long mu = rowmask[r - 1];
        unsigned long long rs = m & ~(m << 1);
        unsigned long long rsu = mu & ~(mu << 1);
        unsigned long long zb = ~m & below;
        int b0 = zb ? (64 - __clzll(zb)) : 0;        // my run start lane
        int n0 = (r << 5) | (int)__popcll(rs & ((b0 == 0) ? 0ull : ((1ull << b0) - 1)));
        bool upC = (mu >> lane) & 1;
        bool upL = (lane > 0)  && ((mu >> (lane - 1)) & 1);
        bool upR = (lane < 63) && ((mu >> (lane + 1)) & 1);
        bool atStart = (lane == b0);
        bool atEnd = (lane == 63) || !((m >> (lane + 1)) & 1);
        auto unode = [&](int lu) {
            unsigned long long belu = (lu == 0) ? 0ull : ((1ull << lu) - 1);
            unsigned long long zbu = ~mu & belu;
            int u0 = zbu ? (64 - __clzll(zbu)) : 0;
            return ((r - 1) << 5) | (int)__popcll(rsu & ((u0 == 0) ? 0ull : ((1ull << u0) - 1)));
        };
        if (upC && (atStart || !upL)) merge_l(n0, unode(lane));
        if (atStart && !upC && upL)   merge_l(n0, unode(lane - 1));
        if (atEnd && !upC && upR)     merge_l(n0, unode(lane + 1));
    }
    __syncthreads();

    // Phase C: run starts compress own node + wave-aggregated length fold
    for (int k = 0; k < TS / 4; k++) {
        int r = (k << 2) | wv;
        unsigned long long m = rowmask[r];
        unsigned long long rs = m & ~(m << 1);
        bool need = (rs >> lane) & 1;                // I am a run start
        int root = 0, len = 0;
        if (need) {
            int node = (r << 5) | (int)__popcll(rs & below);
            unsigned long long za = (~m) >> lane;    // bit0 == my lane
            len = za ? (int)(__ffsll(za) - 1) : (64 - lane);
            // read-only find (stores below only write final roots — safe)
            root = node;
            { int q = lab[root]; while (q != root) { root = q; q = lab[root]; } }
            if (root != node) lab[node] = root;      // sole write to lab[node]
        }
        // one LDS atomic per (wave, distinct root): butterfly-sum lengths
        while (__any(need)) {
            unsigned long long bm = __ballot(need);
            int src = (int)(__ffsll(bm) - 1);
            int rr = __shfl(root, src);
            bool mine = need && (root == rr);
            int v = mine ? len : 0;
            #pragma unroll
            for (int off = 32; off > 0; off >>= 1) v += __shfl_xor(v, off);
            if (lane == src) atomicAdd(&cnt[rr], v);
            if (mine) need = false;
        }
    }
    __syncthreads();

    // Phase D: per-pixel label + fused counts write (zero or root count)
    #pragma unroll
    for (int k = 0; k < TS / 4; k++) {
        int r = (k << 2) | wv;
        unsigned long long m = rowmask[r];
        unsigned long long rs = m & ~(m << 1);
        bool fg = (m >> lane) & 1;
        int g = base + r * Ww + lane;
        int pv = -1, cv = 0;
        if (fg) {
            unsigned long long zb = ~m & below;
            int b0 = zb ? (64 - __clzll(zb)) : 0;
            int node = (r << 5) | (int)__popcll(rs & ((b0 == 0) ? 0ull : ((1ull << b0) - 1)));
            int root = lab[node];                    // broadcast within run
            pv = base + (root >> 5) * Ww + (int)runpos[root];
            if (lane == b0 && root == node) cv = cnt[node];   // I am root pixel
        }
        parent[g] = pv;
        counts[g] = cv;
    }
}

// ---------------- K2: cross-tile border merges (border threads only) -------
// Per batch: group A = rows h%64==0 (16*1024 px), group B = cols w%64 in
// {0,63} (1024*32 px). Corner pixels appear in both groups; merge_uf is
// idempotent so duplicate processing is harmless.

static constexpr int BORDER_A = (Hh / TS) * Ww;                 // 16384
static constexpr int BORDER_PER_B = BORDER_A + Hh * (Ww / TS) * 2;  // 49152

__global__ __launch_bounds__(256) void k_border(int* __restrict__ parent) {
    int b = blockIdx.y;
    int t = blockIdx.x * blockDim.x + threadIdx.x;
    int h, w;
    if (t < BORDER_A) {
        h = (t >> 10) << 6;             // 0,64,...,960
        w = t & 1023;
    } else {
        int t2 = t - BORDER_A;          // 0..32767
        int c = t2 & 31;                // 32 border columns (16 tiles x 2 edges)
        h = t2 >> 5;                    // 0..1023
        w = ((c >> 1) << 6) + ((c & 1) ? (TS - 1) : 0);
    }
    int i = b * HW + h * Ww + w;
    if (parent[i] < 0) return;
    bool hb = (h & (TS - 1)) == 0;
    bool wb = (w & (TS - 1)) == 0;
    bool we = (w & (TS - 1)) == (TS - 1);
    if (wb && w > 0 && parent[i - 1] >= 0) merge_uf(parent, i, i - 1);
    if (h > 0) {
        if (hb && parent[i - Ww] >= 0) merge_uf(parent, i, i - Ww);
        if ((hb | wb) && w > 0 && parent[i - Ww - 1] >= 0) merge_uf(parent, i, i - Ww - 1);
        if ((hb | we) && w < Ww - 1 && parent[i - Ww + 1] >= 0) merge_uf(parent, i, i - Ww + 1);
    }
}

// ---------------- K3: root-only compress + hierarchical count fold ---------
// counts[i] > 0 <=> i is an original tile root. Chains pass only through
// tile roots, so compressing these makes every pixel's root reachable in
// 2 hops. Count folding does one atomic per NON-final tile root; fold
// targets are scattered so they parallelize across batches/components.

__global__ __launch_bounds__(256) void k_roots(int* __restrict__ parent,
                                               int* __restrict__ counts) {
    int i = blockIdx.x * blockDim.x + threadIdx.x;
    int c = counts[i];
    if (c <= 0) return;                      // not an original tile root
    int root = find_root_ro(parent, i);
    if (root != i) {
        parent[i] = root;                    // full compression of root nodes
        atomicAdd(&counts[root], c);         // fold my count into final root
        counts[i] = 0;                       // only final roots keep counts
    }
}

// ---------------- K4a: per-block argmax (NO atomics) -----------------------
// Each block reduces CHUNK=1024 consecutive counts (4/thread, coalesced) to
// one packed (count<<32 | ~index) candidate, plain-stored to blockmax.
// Blocks never straddle a batch (HW % CHUNK == 0).

__global__ __launch_bounds__(256) void k_argmax1(const int* __restrict__ counts,
                                                 unsigned long long* __restrict__ blockmax) {
    int base = blockIdx.x * CHUNK;
    unsigned long long v = 0ull;
    #pragma unroll
    for (int k = 0; k < 4; k++) {
        int i = base + threadIdx.x + k * 256;
        int c = counts[i];
        if (c > 0) {
            unsigned long long o =
                (((unsigned long long)(unsigned)c) << 32) |
                (unsigned long long)(0xFFFFFFFFu - (unsigned)i);
            if (o > v) v = o;
        }
    }
    for (int off = 32; off > 0; off >>= 1) {
        unsigned long long o = __shfl_down(v, off);
        if (o > v) v = o;
    }
    __shared__ unsigned long long sm[4];
    if ((threadIdx.x & 63) == 0) sm[threadIdx.x >> 6] = v;
    __syncthreads();
    if (threadIdx.x == 0) {
        v = sm[0];
        #pragma unroll
        for (int w = 1; w < 4; w++) if (sm[w] > v) v = sm[w];
        blockmax[blockIdx.x] = v;            // plain coalesced store
    }
}

// ---------------- K4b: per-batch final argmax (NO atomics) -----------------

__global__ __launch_bounds__(256) void k_argmax2(const unsigned long long* __restrict__ blockmax,
                                                 unsigned long long* __restrict__ best) {
    int b = blockIdx.x;
    const unsigned long long* src = blockmax + b * BLK1_PER_B;
    unsigned long long v = 0ull;
    #pragma unroll
    for (int k = 0; k < BLK1_PER_B / 256; k++) {
        unsigned long long o = src[threadIdx.x + k * 256];
        if (o > v) v = o;
    }
    for (int off = 32; off > 0; off >>= 1) {
        unsigned long long o = __shfl_down(v, off);
        if (o > v) v = o;
    }
    __shared__ unsigned long long sm[4];
    if ((threadIdx.x & 63) == 0) sm[threadIdx.x >> 6] = v;
    __syncthreads();
    if (threadIdx.x == 0) {
        v = sm[0];
        #pragma unroll
        for (int w = 1; w < 4; w++) if (sm[w] > v) v = sm[w];
        best[b] = v;                         // plain store, one per batch
    }
}

// ---------------- K5: apply mask (2-hop root lookup) -----------------------
// parent[i] is some original tile root (possibly i itself); after k_roots
// every tile root points directly at its final root, so root(i) =
// parent[parent[i]] exactly.

__global__ __launch_bounds__(256) void k_final(const float* __restrict__ x,
                                               const int* __restrict__ parent,
                                               const unsigned long long* __restrict__ best,
                                               float* __restrict__ out) {
    int i = blockIdx.x * blockDim.x + threadIdx.x;
    int b = i >> 20;
    int p = i & (HW - 1);
    unsigned long long bv = best[b];
    int broot = (int)(0xFFFFFFFFu - (unsigned)(bv & 0xFFFFFFFFull));
    int pr = parent[i];
    int a = (pr >= 0) ? pr : 0;              // safe dummy index for bg
    int root = parent[a];                    // mostly-broadcast gather
    bool mask = (pr >= 0) && (root == broot);
    const float* xb = x + ((size_t)b * 2) * (size_t)HW;
    float* ob = out + ((size_t)b * 2) * (size_t)HW;
    float x0 = xb[p];
    float x1 = xb[p + HW];
    ob[p]      = mask ? x0 : 0.0f;
    ob[p + HW] = mask ? x1 : 0.0f;
}

// ---------------- launch ---------------------------------------------------

extern "C" void kernel_launch(void* const* d_in, const int* in_sizes, int n_in,
                              void* d_out, int out_size, void* d_ws, size_t ws_size,
                              hipStream_t stream) {
    const float* x = (const float*)d_in[0];
    float* out = (float*)d_out;

    // workspace layout:
    //   best[16] u64 (256B pad) | parent[NPIX] i32 | counts[NPIX] i32 |
    //   blockmax[NBLK1] u64 (128KB)
    unsigned long long* best = (unsigned long long*)d_ws;
    int* parent = (int*)((char*)d_ws + 256);
    int* counts = parent + NPIX;
    unsigned long long* blockmax = (unsigned long long*)(counts + NPIX);

    dim3 blk(256);
    dim3 grd(NPIX / 256);
    dim3 grd_tiles(BATCH * TILES_PER_IMG);           // 4096 tiles
    dim3 grd_border(BORDER_PER_B / 256, BATCH);      // 192 x 16 blocks

    k_local   <<<grd_tiles, blk, 0, stream>>>(x, parent, counts, best);
    k_border  <<<grd_border, blk, 0, stream>>>(parent);
    k_roots   <<<grd, blk, 0, stream>>>(parent, counts);
    k_argmax1 <<<dim3(NBLK1), blk, 0, stream>>>(counts, blockmax);
    k_argmax2 <<<dim3(BATCH), blk, 0, stream>>>(blockmax, best);
    k_final   <<<grd, blk, 0, stream>>>(x, parent, best, out);
}

// Round 7
// 555.364 us; speedup vs baseline: 1.3167x; 1.0846x over previous
//
#include <hip/hip_runtime.h>
#include <stdint.h>

static constexpr int BATCH = 16;
static constexpr int Hh = 1024;
static constexpr int Ww = 1024;
static constexpr int HW = Hh * Ww;        // 2^20
static constexpr int NPIX = BATCH * HW;   // 2^24
static constexpr int TS = 64;             // tile side (64x64 local CCL)
static constexpr int TILES_PER_IMG = (Hh / TS) * (Ww / TS);   // 256
static constexpr int NODES = TS * 32;     // run nodes: <=32 runs per 64px row

static constexpr int CAPB = 65536;        // root-list capacity per batch (~20x margin)
static constexpr int NB1  = CAPB / 1024;  // argmax1 blocks per batch = 64

// ---------------- global union-find (Komura/Playne atomic min-link) --------

// Path-halving find: ONLY safe during the merge phase (k_border), where the
// merge retry loop re-establishes any link displaced by a racing plain store.
__device__ __forceinline__ int find_root_halve(int* parent, int i) {
    while (true) {
        int p = parent[i];
        if (p == i) return i;
        int gp = parent[p];
        if (gp == p) return p;
        parent[i] = gp;        // plain store of an ancestor — merge-phase safe
        i = gp;
    }
}

// Read-only find: used in k_roots. Safe concurrently with k_roots' own
// parent[g]=final stores because those stores only ever write FINAL roots
// (self-terminating), never mid-chain ancestors.
__device__ __forceinline__ int find_root_ro(const int* parent, int i) {
    int p = parent[i];
    while (p != i) { i = p; p = parent[i]; }
    return i;
}

__device__ __forceinline__ void merge_uf(int* parent, int a, int b) {
    while (true) {
        a = find_root_halve(parent, a);
        b = find_root_halve(parent, b);
        if (a == b) return;
        if (a > b) { int t = a; a = b; b = t; }   // ensure a < b
        int old = atomicMin(&parent[b], a);
        if (old == b) return;   // b was a root and we linked it under a
        b = old;                // someone else linked b first; merge with that
    }
}

// ---------------- K1: per-tile run-based CCL, compact run nodes ------------
// 64x64 tile, 256 threads = 4 waves; wave = full 64-px row, one __ballot per
// row. UF node = (row<<5)|run_index. Vertical merges deduplicated via R1-R3.
// Count fold wave-aggregated into LDS cnt. New Phase E publishes tile roots
// (cnt[node] > 0 <=> final tile root) into a per-batch compact list with ONE
// global atomic per block, and zeroes counts[] only at root pixels.

__global__ __launch_bounds__(256) void k_local(const float* __restrict__ x,
                                               int* __restrict__ parent,
                                               int* __restrict__ counts,
                                               unsigned long long* __restrict__ list,
                                               unsigned* __restrict__ nlist) {
    __shared__ int lab[NODES];
    __shared__ int cnt[NODES];
    __shared__ unsigned char runpos[NODES];
    __shared__ unsigned long long rowmask[TS];
    __shared__ int wbase[4];
    __shared__ int blkbase;

    int tile = blockIdx.x;          // 16 images * 256 tiles
    int b = tile >> 8;
    int t = tile & 255;
    int th = t >> 4, tw = t & 15;
    int h0 = th * TS, w0 = tw * TS;
    const float* xb = x + (size_t)b * 2 * (size_t)HW;
    int base = b * HW + h0 * Ww + w0;   // global idx of local (0,0)
    int wv = threadIdx.x >> 6;
    int lane = threadIdx.x & 63;
    unsigned long long below = (lane == 0) ? 0ull : ((1ull << lane) - 1);

    // node table init (self-roots, zero counts)
    #pragma unroll
    for (int k = 0; k < NODES / 256; k++) {
        int i = threadIdx.x + k * 256;
        lab[i] = i;
        cnt[i] = 0;
    }

    // Phase A: load fg, build row masks, register run starts
    #pragma unroll
    for (int k = 0; k < TS / 4; k++) {
        int r = (k << 2) | wv;
        int off = (h0 + r) * Ww + w0 + lane;
        float x0 = xb[off];
        float x1 = xb[off + HW];
        bool fg = x1 > x0;
        unsigned long long m = __ballot(fg);
        if (lane == 0) rowmask[r] = m;
        unsigned long long rs = m & ~(m << 1);       // run-start mask
        if ((rs >> lane) & 1) {
            int node = (r << 5) | (int)__popcll(rs & below);
            runpos[node] = (unsigned char)lane;
        }
    }
    __syncthreads();

    // LDS union-find on run nodes (path halving; retry loop makes racing
    // ancestor stores safe, same argument as find_root_halve).
    auto find_lh = [&](int i) {
        while (true) {
            int p = lab[i];
            if (p == i) return i;
            int gp = lab[p];
            if (gp == p) return p;
            lab[i] = gp;
            i = gp;
        }
    };
    auto merge_l = [&](int a, int c) {
        while (true) {
            a = find_lh(a); c = find_lh(c);
            if (a == c) return;
            if (a > c) { int tt = a; a = c; c = tt; }
            int old = atomicMin(&lab[c], a);
            if (old == c) return;
            c = old;
        }
    };

    // Phase B: deduplicated vertical run merges
    for (int k = 0; k < TS / 4; k++) {
        int r = (k << 2) | wv;
        if (r == 0) continue;
        unsigned long long m = rowmask[r];
        bool fg = (m >> lane) & 1;
        if (!fg) continue;
        unsigned long long mu = rowmask[r - 1];
        unsigned long long rs = m & ~(m << 1);
        unsigned long long rsu = mu & ~(mu << 1);
        unsigned long long zb = ~m & below;
        int b0 = zb ? (64 - __clzll(zb)) : 0;        // my run start lane
        int n0 = (r << 5) | (int)__popcll(rs & ((b0 == 0) ? 0ull : ((1ull << b0) - 1)));
        bool upC = (mu >> lane) & 1;
        bool upL = (lane > 0)  && ((mu >> (lane - 1)) & 1);
        bool upR = (lane < 63) && ((mu >> (lane + 1)) & 1);
        bool atStart = (lane == b0);
        bool atEnd = (lane == 63) || !((m >> (lane + 1)) & 1);
        auto unode = [&](int lu) {
            unsigned long long belu = (lu == 0) ? 0ull : ((1ull << lu) - 1);
            unsigned long long zbu = ~mu & belu;
            int u0 = zbu ? (64 - __clzll(zbu)) : 0;
            return ((r - 1) << 5) | (int)__popcll(rsu & ((u0 == 0) ? 0ull : ((1ull << u0) - 1)));
        };
        if (upC && (atStart || !upL)) merge_l(n0, unode(lane));
        if (atStart && !upC && upL)   merge_l(n0, unode(lane - 1));
        if (atEnd && !upC && upR)     merge_l(n0, unode(lane + 1));
    }
    __syncthreads();

    // Phase C: run starts compress own node + wave-aggregated length fold
    for (int k = 0; k < TS / 4; k++) {
        int r = (k << 2) | wv;
        unsigned long long m = rowmask[r];
        unsigned long long rs = m & ~(m << 1);
        bool need = (rs >> lane) & 1;                // I am a run start
        int root = 0, len = 0;
        if (need) {
            int node = (r << 5) | (int)__popcll(rs & below);
            unsigned long long za = (~m) >> lane;    // bit0 == my lane
            len = za ? (int)(__ffsll(za) - 1) : (64 - lane);
            // read-only find (stores below only write final roots — safe)
            root = node;
            { int q = lab[root]; while (q != root) { root = q; q = lab[root]; } }
            if (root != node) lab[node] = root;      // sole write to lab[node]
        }
        // one LDS atomic per (wave, distinct root): butterfly-sum lengths
        while (__any(need)) {
            unsigned long long bm = __ballot(need);
            int src = (int)(__ffsll(bm) - 1);
            int rr = __shfl(root, src);
            bool mine = need && (root == rr);
            int v = mine ? len : 0;
            #pragma unroll
            for (int off = 32; off > 0; off >>= 1) v += __shfl_xor(v, off);
            if (lane == src) atomicAdd(&cnt[rr], v);
            if (mine) need = false;
        }
    }
    __syncthreads();

    // Phase D: per-pixel parent write only (counts array no longer streamed)
    #pragma unroll
    for (int k = 0; k < TS / 4; k++) {
        int r = (k << 2) | wv;
        unsigned long long m = rowmask[r];
        unsigned long long rs = m & ~(m << 1);
        bool fg = (m >> lane) & 1;
        int g = base + r * Ww + lane;
        int pv = -1;
        if (fg) {
            unsigned long long zb = ~m & below;
            int b0 = zb ? (64 - __clzll(zb)) : 0;
            int node = (r << 5) | (int)__popcll(rs & ((b0 == 0) ? 0ull : ((1ull << b0) - 1)));
            int root = lab[node];                    // broadcast within run
            pv = base + (root >> 5) * Ww + (int)runpos[root];
        }
        parent[g] = pv;
    }

    // Phase E: publish tile roots to per-batch compact list.
    // cnt[node] > 0 <=> node is a FINAL tile root (folds only target final
    // roots; unregistered nodes keep cnt==0). One global atomic per block.
    int wtot = 0;
    unsigned rootbits = 0;
    #pragma unroll
    for (int k = 0; k < NODES / 256; k++) {
        int node = (k << 8) | threadIdx.x;
        bool isr = cnt[node] > 0;
        if (isr) rootbits |= (1u << k);
        unsigned long long bm = __ballot(isr);
        wtot += (int)__popcll(bm);                   // uniform per wave
    }
    if (lane == 0) wbase[wv] = wtot;
    __syncthreads();
    if (threadIdx.x == 0) {
        int s0 = wbase[0], s1 = wbase[1], s2 = wbase[2], s3 = wbase[3];
        blkbase = (int)atomicAdd(&nlist[b << 5], (unsigned)(s0 + s1 + s2 + s3));
        wbase[0] = 0; wbase[1] = s0; wbase[2] = s0 + s1; wbase[3] = s0 + s1 + s2;
    }
    __syncthreads();
    int woff = blkbase + wbase[wv];
    #pragma unroll
    for (int k = 0; k < NODES / 256; k++) {
        bool isr = (rootbits >> k) & 1;
        unsigned long long bm = __ballot(isr);
        if (isr) {
            int slot = woff + (int)__popcll(bm & below);
            if (slot < CAPB) {
                int node = (k << 8) | threadIdx.x;
                int g = base + (node >> 5) * Ww + (int)runpos[node];
                list[(size_t)b * CAPB + slot] =
                    (((unsigned long long)(unsigned)cnt[node]) << 32) |
                    (unsigned long long)(0xFFFFFFFFu - (unsigned)g);
                counts[g] = 0;                        // sparse accumulator init
            }
        }
        woff += (int)__popcll(bm);
    }
}

// ---------------- K2: cross-tile border merges (border threads only) -------

static constexpr int BORDER_A = (Hh / TS) * Ww;                 // 16384
static constexpr int BORDER_PER_B = BORDER_A + Hh * (Ww / TS) * 2;  // 49152

__global__ __launch_bounds__(256) void k_border(int* __restrict__ parent) {
    int b = blockIdx.y;
    int t = blockIdx.x * blockDim.x + threadIdx.x;
    int h, w;
    if (t < BORDER_A) {
        h = (t >> 10) << 6;             // 0,64,...,960
        w = t & 1023;
    } else {
        int t2 = t - BORDER_A;          // 0..32767
        int c = t2 & 31;                // 32 border columns (16 tiles x 2 edges)
        h = t2 >> 5;                    // 0..1023
        w = ((c >> 1) << 6) + ((c & 1) ? (TS - 1) : 0);
    }
    int i = b * HW + h * Ww + w;
    if (parent[i] < 0) return;
    bool hb = (h & (TS - 1)) == 0;
    bool wb = (w & (TS - 1)) == 0;
    bool we = (w & (TS - 1)) == (TS - 1);
    if (wb && w > 0 && parent[i - 1] >= 0) merge_uf(parent, i, i - 1);
    if (h > 0) {
        if (hb && parent[i - Ww] >= 0) merge_uf(parent, i, i - Ww);
        if ((hb | wb) && w > 0 && parent[i - Ww - 1] >= 0) merge_uf(parent, i, i - Ww - 1);
        if ((hb | we) && w < Ww - 1 && parent[i - Ww + 1] >= 0) merge_uf(parent, i, i - Ww + 1);
    }
}

// ---------------- K3: list-walk compress + wave-aggregated count fold ------
// Processes only the ~2-4K tile-root entries per batch. Compresses each to
// its final root (2-hop invariant for k_final), folds counts with one global
// atomic per (wave, distinct root) — entries are tile-ordered, so waves
// share roots heavily. Rewrites entry low32 = ~final_root for argmax.

__global__ __launch_bounds__(256) void k_roots(int* __restrict__ parent,
                                               int* __restrict__ counts,
                                               unsigned long long* __restrict__ list,
                                               const unsigned* __restrict__ nlist) {
    int b = blockIdx.y;
    int n = (int)nlist[b << 5]; if (n > CAPB) n = CAPB;
    int j = blockIdx.x * 256 + threadIdx.x;
    bool need = j < n;
    int r = 0, c = 0;
    size_t idx = (size_t)b * CAPB + j;
    if (need) {
        unsigned long long e = list[idx];
        int g = (int)(0xFFFFFFFFu - (unsigned)(e & 0xFFFFFFFFull));
        c = (int)(e >> 32);
        r = find_root_ro(parent, g);
        if (r != g) parent[g] = r;               // full compression of roots
        list[idx] = (unsigned long long)(0xFFFFFFFFu - (unsigned)r);
    }
    int lane = threadIdx.x & 63;
    while (__any(need)) {
        unsigned long long bm = __ballot(need);
        int src = (int)(__ffsll(bm) - 1);
        int rr = __shfl(r, src);
        bool mine = need && (r == rr);
        int v = mine ? c : 0;
        #pragma unroll
        for (int off = 32; off > 0; off >>= 1) v += __shfl_xor(v, off);
        if (lane == src) atomicAdd(&counts[rr], v);
        if (mine) need = false;
    }
}

// ---------------- K4a: per-block argmax over root list (NO atomics) --------

__global__ __launch_bounds__(256) void k_argmax1(const unsigned long long* __restrict__ list,
                                                 const int* __restrict__ counts,
                                                 const unsigned* __restrict__ nlist,
                                                 unsigned long long* __restrict__ blockmax) {
    int b = blockIdx.y;
    int n = (int)nlist[b << 5]; if (n > CAPB) n = CAPB;
    unsigned long long v = 0ull;
    #pragma unroll
    for (int k = 0; k < 4; k++) {
        int j = blockIdx.x * 1024 + k * 256 + threadIdx.x;
        if (j < n) {
            unsigned rinv = (unsigned)(list[(size_t)b * CAPB + j] & 0xFFFFFFFFull);
            int r = (int)(0xFFFFFFFFu - rinv);
            int c = counts[r];                   // broadcast-heavy gather
            unsigned long long o =
                (((unsigned long long)(unsigned)c) << 32) | (unsigned long long)rinv;
            if (o > v) v = o;
        }
    }
    for (int off = 32; off > 0; off >>= 1) {
        unsigned long long o = __shfl_down(v, off);
        if (o > v) v = o;
    }
    __shared__ unsigned long long sm[4];
    if ((threadIdx.x & 63) == 0) sm[threadIdx.x >> 6] = v;
    __syncthreads();
    if (threadIdx.x == 0) {
        v = sm[0];
        #pragma unroll
        for (int w = 1; w < 4; w++) if (sm[w] > v) v = sm[w];
        blockmax[b * NB1 + blockIdx.x] = v;
    }
}

// ---------------- K4b: per-batch final argmax (NO atomics) -----------------

__global__ __launch_bounds__(256) void k_argmax2(const unsigned long long* __restrict__ blockmax,
                                                 unsigned long long* __restrict__ best) {
    int b = blockIdx.x;
    unsigned long long v = 0ull;
    if (threadIdx.x < NB1) v = blockmax[b * NB1 + threadIdx.x];
    for (int off = 32; off > 0; off >>= 1) {
        unsigned long long o = __shfl_down(v, off);
        if (o > v) v = o;
    }
    __shared__ unsigned long long sm[4];
    if ((threadIdx.x & 63) == 0) sm[threadIdx.x >> 6] = v;
    __syncthreads();
    if (threadIdx.x == 0) {
        v = sm[0];
        #pragma unroll
        for (int w = 1; w < 4; w++) if (sm[w] > v) v = sm[w];
        best[b] = v;                         // plain store, one per batch
    }
}

// ---------------- K5: apply mask (2-hop root lookup) -----------------------

__global__ __launch_bounds__(256) void k_final(const float* __restrict__ x,
                                               const int* __restrict__ parent,
                                               const unsigned long long* __restrict__ best,
                                               float* __restrict__ out) {
    int i = blockIdx.x * blockDim.x + threadIdx.x;
    int b = i >> 20;
    int p = i & (HW - 1);
    unsigned long long bv = best[b];
    int broot = (int)(0xFFFFFFFFu - (unsigned)(bv & 0xFFFFFFFFull));
    int pr = parent[i];
    int a = (pr >= 0) ? pr : 0;              // safe dummy index for bg
    int root = parent[a];                    // mostly-broadcast gather
    bool mask = (pr >= 0) && (root == broot);
    const float* xb = x + ((size_t)b * 2) * (size_t)HW;
    float* ob = out + ((size_t)b * 2) * (size_t)HW;
    float x0 = xb[p];
    float x1 = xb[p + HW];
    ob[p]      = mask ? x0 : 0.0f;
    ob[p + HW] = mask ? x1 : 0.0f;
}

// ---------------- launch ---------------------------------------------------

extern "C" void kernel_launch(void* const* d_in, const int* in_sizes, int n_in,
                              void* d_out, int out_size, void* d_ws, size_t ws_size,
                              hipStream_t stream) {
    const float* x = (const float*)d_in[0];
    float* out = (float*)d_out;

    // workspace layout:
    //   0:    best[16] u64 (128 B), pad
    //   256:  nlist — 16 u32 counters at 128 B stride (2048 B)
    //   4096: parent[NPIX] i32 (64 MB)
    //   +:    counts[NPIX] i32 (64 MB, sparse-use accumulators)
    //   +:    blockmax[1024] u64 (8 KB)
    //   +:    list[16*CAPB] u64 (8 MB)
    unsigned long long* best = (unsigned long long*)d_ws;
    unsigned* nlist = (unsigned*)((char*)d_ws + 256);
    int* parent = (int*)((char*)d_ws + 4096);
    int* counts = parent + NPIX;
    unsigned long long* blockmax = (unsigned long long*)(counts + NPIX);
    unsigned long long* list = blockmax + 1024;

    dim3 blk(256);
    dim3 grd(NPIX / 256);
    dim3 grd_tiles(BATCH * TILES_PER_IMG);           // 4096 tiles
    dim3 grd_border(BORDER_PER_B / 256, BATCH);      // 192 x 16 blocks
    dim3 grd_roots(CAPB / 256, BATCH);               // 256 x 16 (early-out)
    dim3 grd_arg1(NB1, BATCH);                       // 64 x 16

    hipMemsetAsync(nlist, 0, 2048, stream);          // zero 16 list counters

    k_local   <<<grd_tiles, blk, 0, stream>>>(x, parent, counts, list, nlist);
    k_border  <<<grd_border, blk, 0, stream>>>(parent);
    k_roots   <<<grd_roots, blk, 0, stream>>>(parent, counts, list, nlist);
    k_argmax1 <<<grd_arg1, blk, 0, stream>>>(list, counts, nlist, blockmax);
    k_argmax2 <<<dim3(BATCH), blk, 0, stream>>>(blockmax, best);
    k_final   <<<grd, blk, 0, stream>>>(x, parent, best, out);
}

// Round 9
// 496.133 us; speedup vs baseline: 1.4739x; 1.1194x over previous
//
#include <hip/hip_runtime.h>
#include <stdint.h>

static constexpr int BATCH = 16;
static constexpr int Hh = 1024;
static constexpr int Ww = 1024;
static constexpr int HW = Hh * Ww;        // 2^20
static constexpr int NPIX = BATCH * HW;   // 2^24
static constexpr int TS = 64;             // tile side (64x64 local CCL)
static constexpr int TILES_PER_IMG = (Hh / TS) * (Ww / TS);   // 256
static constexpr int NODES = TS * 32;     // run nodes: <=32 runs per 64px row

static constexpr int CAPB = 65536;        // root-list capacity per batch (~20x margin)
static constexpr int NB1  = CAPB / 1024;  // argmax1 blocks per batch = 64

// ---------------- global union-find (Komura/Playne atomic min-link) --------

// Path-halving find: ONLY safe during the merge phase (k_border), where the
// merge retry loop re-establishes any link displaced by a racing plain store.
__device__ __forceinline__ int find_root_halve(int* parent, int i) {
    while (true) {
        int p = parent[i];
        if (p == i) return i;
        int gp = parent[p];
        if (gp == p) return p;
        parent[i] = gp;        // plain store of an ancestor — merge-phase safe
        i = gp;
    }
}

// Read-only find: used in k_roots. Safe concurrently with k_roots' own
// parent[g]=final stores because those stores only ever write FINAL roots
// (self-terminating), never mid-chain ancestors.
__device__ __forceinline__ int find_root_ro(const int* parent, int i) {
    int p = parent[i];
    while (p != i) { i = p; p = parent[i]; }
    return i;
}

__device__ __forceinline__ void merge_uf(int* parent, int a, int b) {
    while (true) {
        a = find_root_halve(parent, a);
        b = find_root_halve(parent, b);
        if (a == b) return;
        if (a > b) { int t = a; a = b; b = t; }   // ensure a < b
        int old = atomicMin(&parent[b], a);
        if (old == b) return;   // b was a root and we linked it under a
        b = old;                // someone else linked b first; merge with that
    }
}

// ---------------- K1: per-tile run-based CCL, compact run nodes ------------
// 64x64 tile, 256 threads = 4 waves; wave = full 64-px row, one __ballot per
// row. UF node = (row<<5)|run_index. Vertical merges deduplicated via R1-R3.
// Phase C is node-parallel: plain LDS atomicAdd fold. Phase E publishes tile
// roots into a per-batch compact list with ONE global atomic per block.
// NOTE: __syncthreads between node-init and Phase A is REQUIRED — Phase A
// writes runlen/runpos for nodes whose init-zero is owned by OTHER waves
// (the round-8 race: init-after-register erased runs).

__global__ __launch_bounds__(256) void k_local(const float* __restrict__ x,
                                               int* __restrict__ parent,
                                               int* __restrict__ counts,
                                               unsigned long long* __restrict__ list,
                                               unsigned* __restrict__ nlist) {
    __shared__ int lab[NODES];
    __shared__ int cnt[NODES];
    __shared__ unsigned char runpos[NODES];
    __shared__ unsigned char runlen[NODES];
    __shared__ unsigned long long rowmask[TS];
    __shared__ int wbase[4];
    __shared__ int blkbase;

    int tile = blockIdx.x;          // 16 images * 256 tiles
    int b = tile >> 8;
    int t = tile & 255;
    int th = t >> 4, tw = t & 15;
    int h0 = th * TS, w0 = tw * TS;
    const float* xb = x + (size_t)b * 2 * (size_t)HW;
    int base = b * HW + h0 * Ww + w0;   // global idx of local (0,0)
    int wv = threadIdx.x >> 6;
    int lane = threadIdx.x & 63;
    unsigned long long below = (lane == 0) ? 0ull : ((1ull << lane) - 1);

    // node table init (self-roots, zero counts/lengths)
    #pragma unroll
    for (int k = 0; k < NODES / 256; k++) {
        int i = threadIdx.x + k * 256;
        lab[i] = i;
        cnt[i] = 0;
        runlen[i] = 0;
    }
    __syncthreads();   // REQUIRED: Phase A writes other waves' init slots

    // Phase A: load fg, build row masks, register run starts (pos + length)
    #pragma unroll
    for (int k = 0; k < TS / 4; k++) {
        int r = (k << 2) | wv;
        int off = (h0 + r) * Ww + w0 + lane;
        float x0 = xb[off];
        float x1 = xb[off + HW];
        bool fg = x1 > x0;
        unsigned long long m = __ballot(fg);
        if (lane == 0) rowmask[r] = m;
        unsigned long long rs = m & ~(m << 1);       // run-start mask
        if ((rs >> lane) & 1) {
            int node = (r << 5) | (int)__popcll(rs & below);
            runpos[node] = (unsigned char)lane;
            unsigned long long za = (~m) >> lane;    // bit0 == my lane
            runlen[node] = (unsigned char)(za ? (int)(__ffsll(za) - 1) : (64 - lane));
        }
    }
    __syncthreads();

    // LDS union-find on run nodes (path halving; retry loop makes racing
    // ancestor stores safe, same argument as find_root_halve).
    auto find_lh = [&](int i) {
        while (true) {
            int p = lab[i];
            if (p == i) return i;
            int gp = lab[p];
            if (gp == p) return p;
            lab[i] = gp;
            i = gp;
        }
    };
    auto merge_l = [&](int a, int c) {
        while (true) {
            a = find_lh(a); c = find_lh(c);
            if (a == c) return;
            if (a > c) { int tt = a; a = c; c = tt; }
            int old = atomicMin(&lab[c], a);
            if (old == c) return;
            c = old;
        }
    };

    // Phase B: deduplicated vertical run merges
    for (int k = 0; k < TS / 4; k++) {
        int r = (k << 2) | wv;
        if (r == 0) continue;
        unsigned long long m = rowmask[r];
        bool fg = (m >> lane) & 1;
        if (!fg) continue;
        unsigned long long mu = rowmask[r - 1];
        unsigned long long rs = m & ~(m << 1);
        unsigned long long rsu = mu & ~(mu << 1);
        unsigned long long zb = ~m & below;
        int b0 = zb ? (64 - __clzll(zb)) : 0;        // my run start lane
        int n0 = (r << 5) | (int)__popcll(rs & ((b0 == 0) ? 0ull : ((1ull << b0) - 1)));
        bool upC = (mu >> lane) & 1;
        bool upL = (lane > 0)  && ((mu >> (lane - 1)) & 1);
        bool upR = (lane < 63) && ((mu >> (lane + 1)) & 1);
        bool atStart = (lane == b0);
        bool atEnd = (lane == 63) || !((m >> (lane + 1)) & 1);
        auto unode = [&](int lu) {
            unsigned long long belu = (lu == 0) ? 0ull : ((1ull << lu) - 1);
            unsigned long long zbu = ~mu & belu;
            int u0 = zbu ? (64 - __clzll(zbu)) : 0;
            return ((r - 1) << 5) | (int)__popcll(rsu & ((u0 == 0) ? 0ull : ((1ull << u0) - 1)));
        };
        if (upC && (atStart || !upL)) merge_l(n0, unode(lane));
        if (atStart && !upC && upL)   merge_l(n0, unode(lane - 1));
        if (atEnd && !upC && upR)     merge_l(n0, unode(lane + 1));
    }
    __syncthreads();

    // Phase C: node-parallel compress + plain LDS fold (no ballots)
    #pragma unroll
    for (int k = 0; k < NODES / 256; k++) {
        int node = (k << 8) | threadIdx.x;
        int L = (int)runlen[node];
        if (L > 0) {
            // read-only find (stores below only write final roots — safe)
            int root = node;
            { int q = lab[root]; while (q != root) { root = q; q = lab[root]; } }
            if (root != node) lab[node] = root;      // sole write to lab[node]
            atomicAdd(&cnt[root], L);
        }
    }
    __syncthreads();

    // Phase D: per-pixel parent write (lab[node] is now the final tile root)
    #pragma unroll
    for (int k = 0; k < TS / 4; k++) {
        int r = (k << 2) | wv;
        unsigned long long m = rowmask[r];
        unsigned long long rs = m & ~(m << 1);
        bool fg = (m >> lane) & 1;
        int g = base + r * Ww + lane;
        int pv = -1;
        if (fg) {
            unsigned long long zb = ~m & below;
            int b0 = zb ? (64 - __clzll(zb)) : 0;
            int node = (r << 5) | (int)__popcll(rs & ((b0 == 0) ? 0ull : ((1ull << b0) - 1)));
            int root = lab[node];                    // broadcast within run
            pv = base + (root >> 5) * Ww + (int)runpos[root];
        }
        parent[g] = pv;
    }

    // Phase E: publish tile roots to per-batch compact list.
    // cnt[node] > 0 <=> node is a FINAL tile root (folds only target final
    // roots). One global atomic per block.
    int wtot = 0;
    unsigned rootbits = 0;
    #pragma unroll
    for (int k = 0; k < NODES / 256; k++) {
        int node = (k << 8) | threadIdx.x;
        bool isr = cnt[node] > 0;
        if (isr) rootbits |= (1u << k);
        unsigned long long bm = __ballot(isr);
        wtot += (int)__popcll(bm);                   // uniform per wave
    }
    if (lane == 0) wbase[wv] = wtot;
    __syncthreads();
    if (threadIdx.x == 0) {
        int s0 = wbase[0], s1 = wbase[1], s2 = wbase[2], s3 = wbase[3];
        blkbase = (int)atomicAdd(&nlist[b << 5], (unsigned)(s0 + s1 + s2 + s3));
        wbase[0] = 0; wbase[1] = s0; wbase[2] = s0 + s1; wbase[3] = s0 + s1 + s2;
    }
    __syncthreads();
    int woff = blkbase + wbase[wv];
    #pragma unroll
    for (int k = 0; k < NODES / 256; k++) {
        bool isr = (rootbits >> k) & 1;
        unsigned long long bm = __ballot(isr);
        if (isr) {
            int slot = woff + (int)__popcll(bm & below);
            if (slot < CAPB) {
                int node = (k << 8) | threadIdx.x;
                int g = base + (node >> 5) * Ww + (int)runpos[node];
                list[(size_t)b * CAPB + slot] =
                    (((unsigned long long)(unsigned)cnt[node]) << 32) |
                    (unsigned long long)(0xFFFFFFFFu - (unsigned)g);
                counts[g] = 0;                        // sparse accumulator init
            }
        }
        woff += (int)__popcll(bm);
    }
}

// ---------------- K2: run-deduplicated cross-tile border merges ------------
// Row pass: 15 boundary rows x 16 segments of 64px per batch (wave = segment).
// Col pass: 15 col-pairs x 16 row-segments (transposed rules). Each uses the
// k_local-verified R1/R2/R3 run rules -> ~1 merge_uf per connected run pair
// instead of per pixel. Cross-segment corner diagonals handled at lane 0.

__global__ __launch_bounds__(256) void k_border(int* __restrict__ parent) {
    int b = blockIdx.y;
    int wid = (blockIdx.x << 2) | (threadIdx.x >> 6);   // 0..479
    int lane = threadIdx.x & 63;
    unsigned long long below = (lane == 0) ? 0ull : ((1ull << lane) - 1);
    int bbase = b * HW;

    if (wid < 240) {
        // ---- row pass: my row h (B) vs up row h-1 (A) ----
        int s = wid & 15, rb = wid >> 4;
        int h = (rb + 1) << 6;                  // 64..960
        int w0s = s << 6;
        int i  = bbase + h * Ww + w0s + lane;
        int iu = i - Ww;
        int pm = parent[i];
        int pu = parent[iu];
        unsigned long long mB = __ballot(pm >= 0);
        unsigned long long mA = __ballot(pu >= 0);
        if (pm >= 0) {
            unsigned long long zb = ~mB & below;
            int b0 = zb ? (64 - __clzll(zb)) : 0;
            bool upC = (mA >> lane) & 1;
            bool upL = (lane > 0)  && ((mA >> (lane - 1)) & 1);
            bool upR = (lane < 63) && ((mA >> (lane + 1)) & 1);
            bool atStart = (lane == b0);
            bool atEnd = (lane == 63) || !((mB >> (lane + 1)) & 1);
            if (upC && (atStart || !upL)) merge_uf(parent, i, iu);
            if (atStart && !upC && upL)   merge_uf(parent, i, iu - 1);
            if (atEnd && !upC && upR)     merge_uf(parent, i, iu + 1);
        }
        if (lane == 0 && w0s > 0) {
            // corner diagonals across the segment boundary
            int pAp = parent[i - 1];       // (h,   w0s-1)
            int pBp = parent[iu - 1];      // (h-1, w0s-1)
            if (pm >= 0 && pBp >= 0) merge_uf(parent, i, iu - 1);
            if (pu >= 0 && pAp >= 0) merge_uf(parent, iu, i - 1);
        }
    } else {
        // ---- col pass: my col cR (B) vs left col cR-1 (A), runs vertical ----
        int wid2 = wid - 240;
        int s = wid2 & 15, cb = wid2 >> 4;
        int cR = (cb + 1) << 6;                 // 64..960
        int r = (s << 6) + lane;
        int iR = bbase + r * Ww + cR;
        int iL = iR - 1;
        int pB = parent[iR];
        int pA = parent[iL];
        unsigned long long mB = __ballot(pB >= 0);
        unsigned long long mA = __ballot(pA >= 0);
        if (pB >= 0) {
            unsigned long long zb = ~mB & below;
            int b0 = zb ? (64 - __clzll(zb)) : 0;
            bool upC = (mA >> lane) & 1;
            bool upL = (lane > 0)  && ((mA >> (lane - 1)) & 1);
            bool upR = (lane < 63) && ((mA >> (lane + 1)) & 1);
            bool atStart = (lane == b0);
            bool atEnd = (lane == 63) || !((mB >> (lane + 1)) & 1);
            if (upC && (atStart || !upL)) merge_uf(parent, iR, iL);
            if (atStart && !upC && upL)   merge_uf(parent, iR, iL - Ww);
            if (atEnd && !upC && upR)     merge_uf(parent, iR, iL + Ww);
        }
        if (lane == 0 && s > 0) {
            // corner diagonals across the row-segment boundary
            int aL = parent[iL - Ww];      // (r-1, cR-1)
            int aR = parent[iR - Ww];      // (r-1, cR)
            if (pB >= 0 && aL >= 0) merge_uf(parent, iR, iL - Ww);
            if (pA >= 0 && aR >= 0) merge_uf(parent, iL, iR - Ww);
        }
    }
}

// ---------------- K3: list-walk compress + wave-aggregated count fold ------

__global__ __launch_bounds__(256) void k_roots(int* __restrict__ parent,
                                               int* __restrict__ counts,
                                               unsigned long long* __restrict__ list,
                                               const unsigned* __restrict__ nlist) {
    int b = blockIdx.y;
    int n = (int)nlist[b << 5]; if (n > CAPB) n = CAPB;
    int j = blockIdx.x * 256 + threadIdx.x;
    bool need = j < n;
    int r = 0, c = 0;
    size_t idx = (size_t)b * CAPB + j;
    if (need) {
        unsigned long long e = list[idx];
        int g = (int)(0xFFFFFFFFu - (unsigned)(e & 0xFFFFFFFFull));
        c = (int)(e >> 32);
        r = find_root_ro(parent, g);
        if (r != g) parent[g] = r;               // full compression of roots
        list[idx] = (unsigned long long)(0xFFFFFFFFu - (unsigned)r);
    }
    int lane = threadIdx.x & 63;
    while (__any(need)) {
        unsigned long long bm = __ballot(need);
        int src = (int)(__ffsll(bm) - 1);
        int rr = __shfl(r, src);
        bool mine = need && (r == rr);
        int v = mine ? c : 0;
        #pragma unroll
        for (int off = 32; off > 0; off >>= 1) v += __shfl_xor(v, off);
        if (lane == src) atomicAdd(&counts[rr], v);
        if (mine) need = false;
    }
}

// ---------------- K4a: per-block argmax over root list (NO atomics) --------

__global__ __launch_bounds__(256) void k_argmax1(const unsigned long long* __restrict__ list,
                                                 const int* __restrict__ counts,
                                                 const unsigned* __restrict__ nlist,
                                                 unsigned long long* __restrict__ blockmax) {
    int b = blockIdx.y;
    int n = (int)nlist[b << 5]; if (n > CAPB) n = CAPB;
    unsigned long long v = 0ull;
    #pragma unroll
    for (int k = 0; k < 4; k++) {
        int j = blockIdx.x * 1024 + k * 256 + threadIdx.x;
        if (j < n) {
            unsigned rinv = (unsigned)(list[(size_t)b * CAPB + j] & 0xFFFFFFFFull);
            int r = (int)(0xFFFFFFFFu - rinv);
            int c = counts[r];                   // broadcast-heavy gather
            unsigned long long o =
                (((unsigned long long)(unsigned)c) << 32) | (unsigned long long)rinv;
            if (o > v) v = o;
        }
    }
    for (int off = 32; off > 0; off >>= 1) {
        unsigned long long o = __shfl_down(v, off);
        if (o > v) v = o;
    }
    __shared__ unsigned long long sm[4];
    if ((threadIdx.x & 63) == 0) sm[threadIdx.x >> 6] = v;
    __syncthreads();
    if (threadIdx.x == 0) {
        v = sm[0];
        #pragma unroll
        for (int w = 1; w < 4; w++) if (sm[w] > v) v = sm[w];
        blockmax[b * NB1 + blockIdx.x] = v;
    }
}

// ---------------- K4b: per-batch final argmax (NO atomics) -----------------

__global__ __launch_bounds__(256) void k_argmax2(const unsigned long long* __restrict__ blockmax,
                                                 unsigned long long* __restrict__ best) {
    int b = blockIdx.x;
    unsigned long long v = 0ull;
    if (threadIdx.x < NB1) v = blockmax[b * NB1 + threadIdx.x];
    for (int off = 32; off > 0; off >>= 1) {
        unsigned long long o = __shfl_down(v, off);
        if (o > v) v = o;
    }
    __shared__ unsigned long long sm[4];
    if ((threadIdx.x & 63) == 0) sm[threadIdx.x >> 6] = v;
    __syncthreads();
    if (threadIdx.x == 0) {
        v = sm[0];
        #pragma unroll
        for (int w = 1; w < 4; w++) if (sm[w] > v) v = sm[w];
        best[b] = v;                         // plain store, one per batch
    }
}

// ---------------- K5: apply mask, float4-vectorized (2-hop root lookup) ----

__global__ __launch_bounds__(256) void k_final(const float4* __restrict__ x4,
                                               const int4* __restrict__ parent4,
                                               const int* __restrict__ parent,
                                               const unsigned long long* __restrict__ best,
                                               float4* __restrict__ out4) {
    int i = blockIdx.x * blockDim.x + threadIdx.x;    // quad index
    int b = i >> 18;                                   // (i*4) >> 20
    int q = i & (HW / 4 - 1);
    unsigned long long bv = best[b];
    int broot = (int)(0xFFFFFFFFu - (unsigned)(bv & 0xFFFFFFFFull));
    int4 pr = parent4[(size_t)b * (HW / 4) + q];
    const float4* xb = x4 + (size_t)b * 2 * (HW / 4);
    float4 x0 = xb[q];
    float4 x1 = xb[q + HW / 4];
    int a0 = pr.x >= 0 ? pr.x : 0;
    int a1 = pr.y >= 0 ? pr.y : 0;
    int a2 = pr.z >= 0 ? pr.z : 0;
    int a3 = pr.w >= 0 ? pr.w : 0;
    bool m0 = pr.x >= 0 && parent[a0] == broot;
    bool m1 = pr.y >= 0 && parent[a1] == broot;
    bool m2 = pr.z >= 0 && parent[a2] == broot;
    bool m3 = pr.w >= 0 && parent[a3] == broot;
    float4 o0, o1;
    o0.x = m0 ? x0.x : 0.0f; o0.y = m1 ? x0.y : 0.0f;
    o0.z = m2 ? x0.z : 0.0f; o0.w = m3 ? x0.w : 0.0f;
    o1.x = m0 ? x1.x : 0.0f; o1.y = m1 ? x1.y : 0.0f;
    o1.z = m2 ? x1.z : 0.0f; o1.w = m3 ? x1.w : 0.0f;
    float4* ob = out4 + (size_t)b * 2 * (HW / 4);
    ob[q]          = o0;
    ob[q + HW / 4] = o1;
}

// ---------------- launch ---------------------------------------------------

extern "C" void kernel_launch(void* const* d_in, const int* in_sizes, int n_in,
                              void* d_out, int out_size, void* d_ws, size_t ws_size,
                              hipStream_t stream) {
    const float* x = (const float*)d_in[0];
    float* out = (float*)d_out;

    // workspace layout:
    //   0:    best[16] u64 (128 B), pad
    //   256:  nlist — 16 u32 counters at 128 B stride (2048 B)
    //   4096: parent[NPIX] i32 (64 MB)
    //   +:    counts[NPIX] i32 (64 MB, sparse-use accumulators)
    //   +:    blockmax[1024] u64 (8 KB)
    //   +:    list[16*CAPB] u64 (8 MB)
    unsigned long long* best = (unsigned long long*)d_ws;
    unsigned* nlist = (unsigned*)((char*)d_ws + 256);
    int* parent = (int*)((char*)d_ws + 4096);
    int* counts = parent + NPIX;
    unsigned long long* blockmax = (unsigned long long*)(counts + NPIX);
    unsigned long long* list = blockmax + 1024;

    dim3 blk(256);
    dim3 grd_tiles(BATCH * TILES_PER_IMG);           // 4096 tiles
    dim3 grd_border(120, BATCH);                     // 480 waves per batch
    dim3 grd_roots(CAPB / 256, BATCH);               // 256 x 16 (early-out)
    dim3 grd_arg1(NB1, BATCH);                       // 64 x 16
    dim3 grd_final(NPIX / 4 / 256);                  // 16384 blocks

    hipMemsetAsync(nlist, 0, 2048, stream);          // zero 16 list counters

    k_local   <<<grd_tiles, blk, 0, stream>>>(x, parent, counts, list, nlist);
    k_border  <<<grd_border, blk, 0, stream>>>(parent);
    k_roots   <<<grd_roots, blk, 0, stream>>>(parent, counts, list, nlist);
    k_argmax1 <<<grd_arg1, blk, 0, stream>>>(list, counts, nlist, blockmax);
    k_argmax2 <<<dim3(BATCH), blk, 0, stream>>>(blockmax, best);
    k_final   <<<grd_final, blk, 0, stream>>>((const float4*)x, (const int4*)parent,
                                              parent, best, (float4*)out);
}